// Round 8
// baseline (938.048 us; speedup 1.0000x reference)
//
#include <hip/hip_runtime.h>
#include <stdint.h>
#include <math.h>

// MetropolisHastingsSampler: 2176-step serial MH chain, D=512, H=1024.
//   K1 (fused): RNG (bit-exact JAX threefry, partitionable) writes A rows +
//       U, then same block runs the f64-accum GEMM Z = A @ W1 (identical
//       summation order to R7 -> Z bit-identical).
//   K2: chain. block 0 = sequential chain; blocks 1..254 = DVFS fillers;
//       block 255 = CLOCK PROBE: 307,200 dependent FMAs = 1.2288M cyc.
//       At 2.4 GHz probe (512us) hides under chain (~715us) -> free.
//       If clock is derated, chain dispatch dur = 1.2288e6/f  -> read f.
//   R8 chain diet: A/Z/U padded (+4 rows) so per-step prefetch clamps are
//       deleted (garbage-padding safe: tail prefetches never consumed live).
// Workspace: A(2180x512) | Z(2181x1024) | U(2180) | flag  ~= 12.8 MiB.

#define T_TOTAL 2176
#define NROWS   2177
#define NBURN   128
#define DDIM    512
#define HDIM    1024
#define DONE_FLAG 0x13572468u

// ---------------- threefry2x32 (JAX-exact) ----------------
__device__ __forceinline__ uint2 tf2x32(uint32_t k0, uint32_t k1,
                                        uint32_t x0, uint32_t x1) {
  uint32_t ks2 = k0 ^ k1 ^ 0x1BD11BDAu;
  x0 += k0; x1 += k1;
#define TF_R(r) { x0 += x1; x1 = (x1 << (r)) | (x1 >> (32 - (r))); x1 ^= x0; }
  TF_R(13) TF_R(15) TF_R(26) TF_R(6)
  x0 += k1;  x1 += ks2 + 1u;
  TF_R(17) TF_R(29) TF_R(16) TF_R(24)
  x0 += ks2; x1 += k0 + 2u;
  TF_R(13) TF_R(15) TF_R(26) TF_R(6)
  x0 += k0;  x1 += k1 + 3u;
  TF_R(17) TF_R(29) TF_R(16) TF_R(24)
  x0 += k1;  x1 += ks2 + 4u;
  TF_R(13) TF_R(15) TF_R(26) TF_R(6)
  x0 += ks2; x1 += k0 + 5u;
#undef TF_R
  return make_uint2(x0, x1);
}

// ---------------- XLA ErfInv f32 (Giles polynomial) ----------------
__device__ __forceinline__ float erfinv_xla(float x) {
  float w = -log1pf(-x * x);
  float p;
  if (w < 5.0f) {
    w = w - 2.5f;
    p = 2.81022636e-08f;
    p = fmaf(p, w, 3.43273939e-07f);
    p = fmaf(p, w, -3.5233877e-06f);
    p = fmaf(p, w, -4.39150654e-06f);
    p = fmaf(p, w, 0.00021858087f);
    p = fmaf(p, w, -0.00125372503f);
    p = fmaf(p, w, -0.00417768164f);
    p = fmaf(p, w, 0.246640727f);
    p = fmaf(p, w, 1.50140941f);
  } else {
    w = sqrtf(w) - 3.0f;
    p = -0.000200214257f;
    p = fmaf(p, w, 0.000100950558f);
    p = fmaf(p, w, 0.00134934322f);
    p = fmaf(p, w, -0.00367342844f);
    p = fmaf(p, w, 0.00573950773f);
    p = fmaf(p, w, -0.0076224613f);
    p = fmaf(p, w, 0.00943887047f);
    p = fmaf(p, w, 1.00167406f);
    p = fmaf(p, w, 2.83297682f);
  }
  return p * x;
}

__device__ __forceinline__ float normal_from_bits(uint32_t bits) {
  const float lo = -0.99999994f;  // -(1 - 2^-24)
  float u01 = __uint_as_float(0x3f800000u | (bits >> 9)) - 1.0f;
  float v = u01 * 2.0f + lo;
  v = fmaxf(lo, v);
  return 1.41421356237309515f * erfinv_xla(v);
}

// ---------------- fast tanh via hardware exp2 ----------------
__device__ __forceinline__ float tanh_fast(float x) {
  float a = x * 2.88539008177792681472f;       // 2*log2(e)
#if __has_builtin(__builtin_amdgcn_exp2f)
  float e = __builtin_amdgcn_exp2f(a);
#else
  float e = exp2f(a);
#endif
  float r = __builtin_amdgcn_rcpf(e + 1.0f);
  return fmaf(-2.0f, r, 1.0f);
}

// ---------------- K1: fused RNG + GEMM ----------------
// Block b owns rows r0=8b .. r0+7. Phase 1: generate A rows (+x0 row, +U),
// write global. Phase 2 (after barrier): f64-accum GEMM, reading A rows
// just written (L2-hot). Summation order identical to R7's gemm_kernel.
__global__ void __launch_bounds__(512) rng_gemm_kernel(
    const float* __restrict__ x0, const float* __restrict__ W1,
    float* A, float* __restrict__ Z, float* __restrict__ U) {
  const int r0 = blockIdx.x * 8;
  const int tid = threadIdx.x;

  // ---- phase 1: RNG ----
  const int j = tid & 255;
  for (int k = 0; k < 4; ++k) {
    int rr = r0 + 2 * k + (tid >> 8);
    if (rr == 0) {
      A[j] = x0[j];
      A[j + 256] = x0[j + 256];
    } else if (rr < NROWS) {
      uint32_t t = (uint32_t)(rr - 1);
      uint2 kt = tf2x32(0u, 1u, 0u, t);
      uint2 kn = tf2x32(kt.x, kt.y, 0u, 0u);
      uint2 e0 = tf2x32(kn.x, kn.y, 0u, (uint32_t)j);
      uint2 e1 = tf2x32(kn.x, kn.y, 0u, (uint32_t)(j + 256));
      A[(size_t)rr * DDIM + j]       = normal_from_bits(e0.x ^ e0.y) * 0.1f;
      A[(size_t)rr * DDIM + j + 256] = normal_from_bits(e1.x ^ e1.y) * 0.1f;
    }
  }
  if (tid < 8) {
    int rr = r0 + tid;
    if (rr >= 1 && rr < NROWS) {
      uint32_t t = (uint32_t)(rr - 1);
      uint2 kt = tf2x32(0u, 1u, 0u, t);
      uint2 ku = tf2x32(kt.x, kt.y, 0u, 1u);
      uint2 eu = tf2x32(ku.x, ku.y, 0u, 0u);
      U[t] = __uint_as_float(0x3f800000u | ((eu.x ^ eu.y) >> 9)) - 1.0f;
    }
  }
  __syncthreads();   // A writes drained to L2; L1 has no stale copy (1st touch)

  // ---- phase 2: GEMM ----
  const int c0 = tid, c1 = tid + 512;
  double acc[8][2];
#pragma unroll
  for (int r = 0; r < 8; ++r) { acc[r][0] = 0.0; acc[r][1] = 0.0; }
  for (int d = 0; d < 512; d += 4) {
    double wA[4], wB[4];
#pragma unroll
    for (int jj = 0; jj < 4; ++jj) {
      wA[jj] = (double)W1[(size_t)(d + jj) * 1024 + c0];
      wB[jj] = (double)W1[(size_t)(d + jj) * 1024 + c1];
    }
#pragma unroll
    for (int r = 0; r < 8; ++r) {
      int rr = r0 + r; if (rr >= NROWS) rr = NROWS - 1;   // uniform clamp
      const float4 a4 = *(const float4*)(A + (size_t)rr * 512 + d);
      double a0 = (double)a4.x, a1 = (double)a4.y;
      double a2 = (double)a4.z, a3 = (double)a4.w;
      acc[r][0] += (a0 * wA[0] + a1 * wA[1]) + (a2 * wA[2] + a3 * wA[3]);
      acc[r][1] += (a0 * wB[0] + a1 * wB[1]) + (a2 * wB[2] + a3 * wB[3]);
    }
  }
  const int rmax = (NROWS - r0 < 8) ? (NROWS - r0) : 8;
  for (int r = 0; r < rmax; ++r) {
    Z[(size_t)(r0 + r) * 1024 + c0] = (float)acc[r][0];
    Z[(size_t)(r0 + r) * 1024 + c1] = (float)acc[r][1];
  }
}

// ---------------- DPP wave64 sum-reduce (result in lane 63) ----------------
#define DPP_ADD(v, ctrl)                                                     \
  v += __int_as_float(__builtin_amdgcn_update_dpp(                           \
      0, __float_as_int(v), (ctrl), 0xF, 0xF, true))

__device__ __forceinline__ float wave_reduce_to_last(float v) {
  DPP_ADD(v, 0xB1);   // quad_perm xor1
  DPP_ADD(v, 0x4E);   // quad_perm xor2
  DPP_ADD(v, 0x141);  // row_half_mirror
  DPP_ADD(v, 0x140);  // row_mirror -> row16 totals
  DPP_ADD(v, 0x142);  // row_bcast15
  DPP_ADD(v, 0x143);  // row_bcast31 -> lane 63 wave total
  return v;
}

// Execution barrier with LDS-visibility only (no vmcnt drain).
#define BAR() asm volatile("s_waitcnt lgkmcnt(0)\n\ts_barrier" ::: "memory")

// ---------------- K2: chain + fillers + clock probe ----------------
__global__ void __launch_bounds__(256) chain_kernel(
    const float* __restrict__ Z, const float* __restrict__ A,
    const float* __restrict__ U, const float* __restrict__ x0,
    const float* __restrict__ b1, const float* __restrict__ W2,
    const float* __restrict__ b2, float* __restrict__ out,
    unsigned* __restrict__ flag) {
  const int tid = threadIdx.x;

  if (blockIdx.x == 255) {
    // CLOCK PROBE: 1200*256 = 307,200 dependent FMAs = 1.2288M cyc (4 cyc
    // per dep fma, m07). Hidden under the chain at 2.4 GHz (512us < chain);
    // if SCLK is derated the dispatch dur reads it: f = 1.2288e6/dur_us.
    float a = (float)tid * 1.1920929e-7f + 0.5f;
    for (int i = 0; i < 1200; ++i) {
#pragma unroll
      for (int jj = 0; jj < 256; ++jj) a = fmaf(a, 0.99999988f, 1.0e-7f);
    }
    if (a == 123456.75f) out[0] = a;   // unreachable; defeats DCE
    return;
  }
  if (blockIdx.x != 0) {
    // DVFS keeper (unchanged from R7): bounded latency-bound fma spin.
    float acc = (float)tid * 1.0e-6f;
    for (int i = 0; i < 4000; ++i) {
#pragma unroll
      for (int jj = 0; jj < 256; ++jj) acc = fmaf(acc, 0.99999988f, 1.0e-7f);
      unsigned f = __hip_atomic_load(flag, __ATOMIC_RELAXED,
                                     __HIP_MEMORY_SCOPE_AGENT);
      if (f == DONE_FLAG) break;
    }
    if (acc == 123456.75f && tid == 1023) out[0] = acc;  // never true
    return;
  }

  const int lane = tid & 63;
  const int wid = tid >> 6;
  __shared__ __align__(16) float wsum[2][4];
  __shared__ float Uld[T_TOTAL + 4];

  const float4* Zv = (const float4*)Z;   // 256 float4 per H-row
  const float2* Av = (const float2*)A;   // 256 float2 per D-row

  // preload uniforms (padded; pad entries read but never consumed live)
  for (int i = tid; i < T_TOTAL + 4; i += 256) Uld[i] = U[i];

  const float4 w2v = ((const float4*)W2)[tid];
  const float4 b1v = ((const float4*)b1)[tid];
  const float b2v = b2[0];

  // prologue + steady-state buffer loads
  float4 z0r = Zv[tid];                  // Z row 0
  float4 zr1 = Zv[256 + tid];            // Z row 1 (candidate 0)
  float4 zS0 = Zv[512 + tid];            // Z row 2 (parity-0 buffer)
  float4 zS1 = Zv[768 + tid];            // Z row 3 (parity-1 buffer)
  float2 dS0 = Av[256 + tid];            // A row 1
  float2 dS1 = Av[512 + tid];            // A row 2

  double Y0 = (double)z0r.x + (double)b1v.x;
  double Y1 = (double)z0r.y + (double)b1v.y;
  double Y2 = (double)z0r.z + (double)b1v.z;
  double Y3 = (double)z0r.w + (double)b1v.w;

  float xa = x0[2 * tid], xb = x0[2 * tid + 1];

  __syncthreads();                       // Uld visible to all waves
  float uu0 = Uld[0];
  float uS0 = Uld[1];
  float uS1 = Uld[2];

  // ---- prologue: p = psi2(x0) ----
  {
    float g0 = tanh_fast((float)Y0);
    float g1 = tanh_fast((float)Y1);
    float g2 = tanh_fast((float)Y2);
    float g3 = tanh_fast((float)Y3);
    float tm = fmaf(g3, w2v.w, fmaf(g2, w2v.z, fmaf(g1, w2v.y, g0 * w2v.x)));
    tm = wave_reduce_to_last(tm);
    if (lane == 63) wsum[1][wid] = tm;
  }
  __syncthreads();
  float4 pp = *(const float4*)wsum[1];
  float m0 = ((pp.x + pp.y) + (pp.z + pp.w)) + b2v;
  float p = m0 * m0;
  float um = uu0 * (p + 1e-12f);         // accept_0 iff um < q_0

  // candidate for decision 0: C = Y + Z row 1
  double C0 = Y0 + (double)zr1.x;
  double C1 = Y1 + (double)zr1.y;
  double C2 = Y2 + (double)zr1.z;
  double C3 = Y3 + (double)zr1.w;
  {
    float g0 = tanh_fast((float)C0);
    float g1 = tanh_fast((float)C1);
    float g2 = tanh_fast((float)C2);
    float g3 = tanh_fast((float)C3);
    float tm = fmaf(g3, w2v.w, fmaf(g2, w2v.z, fmaf(g1, w2v.y, g0 * w2v.x)));
    tm = wave_reduce_to_last(tm);
    if (lane == 63) wsum[0][wid] = tm;
  }
  __syncthreads();

  // Per-step macro; arrays padded so indices t+3 / t+4 need no clamps.
#define STEP(t, ZB, DB, UB, W_CUR, W_NXT)                                    \
  {                                                                          \
    const float4 p4 = *(const float4*)wsum[W_CUR];                           \
    float u_new = Uld[(t) + 3];                                              \
    float m = ((p4.x + p4.y) + (p4.z + p4.w)) + b2v;                         \
    float q = m * m;                                                         \
    bool acc = um < q;                                                       \
    Y0 = acc ? C0 : Y0;  Y1 = acc ? C1 : Y1;                                 \
    Y2 = acc ? C2 : Y2;  Y3 = acc ? C3 : Y3;                                 \
    p  = acc ? q : p;                                                        \
    xa = acc ? xa + DB.x : xa;                                               \
    xb = acc ? xb + DB.y : xb;                                               \
    if ((t) >= NBURN) {                                                      \
      float2 o; o.x = xa; o.y = xb;                                          \
      *(float2*)(out + (size_t)((t) - NBURN) * DDIM + 2 * tid) = o;          \
    }                                                                        \
    um = UB * (p + 1e-12f);                                                  \
    C0 = Y0 + (double)ZB.x;                                                  \
    C1 = Y1 + (double)ZB.y;                                                  \
    C2 = Y2 + (double)ZB.z;                                                  \
    C3 = Y3 + (double)ZB.w;                                                  \
    ZB = Zv[(size_t)((t) + 4) * 256 + tid];                                  \
    DB = Av[(size_t)((t) + 3) * 256 + tid];                                  \
    float g0 = tanh_fast((float)C0);                                         \
    float g1 = tanh_fast((float)C1);                                         \
    float g2 = tanh_fast((float)C2);                                         \
    float g3 = tanh_fast((float)C3);                                         \
    float tm = fmaf(g3, w2v.w, fmaf(g2, w2v.z, fmaf(g1, w2v.y, g0 * w2v.x)));\
    tm = wave_reduce_to_last(tm);                                            \
    if (lane == 63) wsum[W_NXT][wid] = tm;                                   \
    UB = u_new;                                                              \
    BAR();                                                                   \
  }

  for (int t = 0; t < T_TOTAL; t += 2) {
    STEP(t,     zS0, dS0, uS0, 0, 1);
    STEP(t + 1, zS1, dS1, uS1, 1, 0);
  }
#undef STEP

  if (tid == 0) {
    __hip_atomic_store(flag, DONE_FLAG, __ATOMIC_RELAXED,
                       __HIP_MEMORY_SCOPE_AGENT);
  }
}

extern "C" void kernel_launch(void* const* d_in, const int* in_sizes, int n_in,
                              void* d_out, int out_size, void* d_ws, size_t ws_size,
                              hipStream_t stream) {
  const float* x0 = (const float*)d_in[0];
  const float* W1 = (const float*)d_in[1];
  const float* b1 = (const float*)d_in[2];
  const float* W2 = (const float*)d_in[3];
  const float* b2 = (const float*)d_in[4];
  float* out = (float*)d_out;

  char* ws = (char*)d_ws;
  // Padded: A 2180 rows (4,464,640 B) | Z 2181 rows (8,933,376 B) |
  //         U 2180 (8,720 B) | flag (4 B).  ~12.79 MiB total.
  float* A = (float*)ws;
  float* Z = (float*)(ws + 4464640);
  float* U = (float*)(ws + 4464640 + 8933376);
  unsigned* flag = (unsigned*)(ws + 4464640 + 8933376 + 8720);

  rng_gemm_kernel<<<273, 512, 0, stream>>>(x0, W1, A, Z, U);
  chain_kernel<<<256, 256, 0, stream>>>(Z, A, U, x0, b1, W2, b2, out, flag);
}